// Round 2
// baseline (142.400 us; speedup 1.0000x reference)
//
#include <hip/hip_runtime.h>
#include <hip/hip_bf16.h>
#include <math.h>

#define NH 64
#define NG 32

// wave-uniform lane broadcast (lane index must be uniform) -> v_readlane, SGPR result
__device__ __forceinline__ float bcast(float v, int l) {
    return __int_as_float(__builtin_amdgcn_readlane(__float_as_int(v), l));
}

// One wave (64 lanes) per catchment s; lane = hidden index h.
// State S,H in registers; 1000-step recurrence; chunked (64 t at a time):
//  phase A: lane i computes forcing-derived (Ps,Pl,E,Ta) for timestep t0+i in parallel
//  phase B: 64 serial steps, per-step scalars via v_readlane; per-step ds_write of y-contrib
//  phase C: lane t row-sums its timestep's 64 contributions from padded LDS, stores fp32
__global__ __launch_bounds__(64) void waternet_kernel(
    const float* __restrict__ x,   // [nt, ns, 4] fp32: P,E,T1,T2
    const float* __restrict__ xc,  // [ns, NG]    fp32
    const float* __restrict__ W3,  // [4*NH, NG]  fp32
    const float* __restrict__ b3,  // [4*NH]      fp32
    float* __restrict__ out,       // [nt, ns]    fp32
    int nt, int ns)
{
    const int s    = blockIdx.x;
    const int lane = threadIdx.x;           // 0..63 == h
    __shared__ float lds[NH * (NH + 1)];    // padded: step-row stride 65 -> conflict-free row reads

    // ---- static gates: w = xc[s,:] @ W3^T + b3 ; each lane does its 4 dot products ----
    const float* xcs = xc + (size_t)s * NG;
    float a0 = 0.f, a1 = 0.f, a2 = 0.f, a3 = 0.f;
    #pragma unroll
    for (int g = 0; g < NG; ++g) {
        const float xv = xcs[g];                       // wave-uniform broadcast load
        a0 = fmaf(xv, W3[(0 * NH + lane) * NG + g], a0);
        a1 = fmaf(xv, W3[(1 * NH + lane) * NG + g], a1);
        a2 = fmaf(xv, W3[(2 * NH + lane) * NG + g], a2);
        a3 = fmaf(xv, W3[(3 * NH + lane) * NG + g], a3);
    }
    const float wm = a0 + b3[0 * NH + lane];
    const float we = a1 + b3[1 * NH + lane];
    const float wo = a2 + b3[2 * NH + lane];
    const float wa = a3 + b3[3 * NH + lane];

    const float gm = expf(wm) + 1.0f;                  // melt gate
    const float ge = 1.0f / (1.0f + expf(-we));        // ET gate
    const float go = 1.0f / (1.0f + expf(-wo));        // outflow gate
    // softmax(wa) across the 64 lanes
    float mx = wa;
    #pragma unroll
    for (int o = 32; o; o >>= 1) mx = fmaxf(mx, __shfl_xor(mx, o, 64));
    const float ex = expf(wa - mx);
    float sm = ex;
    #pragma unroll
    for (int o = 32; o; o >>= 1) sm += __shfl_xor(sm, o, 64);
    const float ga = ex / sm;

    const float gq = go * ga;      // y contrib   = Hn * gq
    const float gk = 1.0f - go;    // H carryover = Hn * gk   (Hn - Hn*go)

    float S = 0.0f, H = 0.0f;

    for (int t0 = 0; t0 < nt; t0 += NH) {
        const int cnt = min(NH, nt - t0);
        const int tl  = t0 + ((lane < cnt) ? lane : 0);

        // phase A: per-lane forcing for timestep tl (parallel across 64 future steps)
        const float4 f = *reinterpret_cast<const float4*>(x + ((size_t)tl * ns + s) * 4);
        const float P  = f.x;
        const float E  = f.y;
        const float T1 = f.z;
        const float T2 = f.w;
        const float Ta = 0.5f * (T1 + T2);
        float rP;
        if (T1 >= 0.0f)       rP = 1.0f;               // melted
        else if (T2 <= 0.0f)  rP = 0.0f;               // frozen
        else {
            float arg = (T1 + T2) / (T2 - T1);
            arg = fminf(1.0f, fmaxf(-1.0f, arg));
            rP = 1.0f - acosf(arg) * (1.0f / 3.1415f); // module hard-codes 3.1415
        }
        const float Ps = (1.0f - rP) * P;
        const float Pl = rP * P;

        __syncthreads();   // WAR: previous chunk's row-reads must finish before rewriting lds

        // phase B: serial recurrence, 64-wide over h
        for (int j = 0; j < cnt; ++j) {
            const float Psj = bcast(Ps, j);
            const float Plj = bcast(Pl, j);
            const float Ej  = bcast(E,  j);
            const float Taj = bcast(Ta, j);
            const float Sm  = fminf(S, fmaxf(Taj * gm, 0.0f));          // snowmelt
            const float Hn  = fmaxf(H + Sm + (Plj - Ej * ge), 0.0f);    // bucket after in/out
            S = S + Psj - Sm;
            H = Hn * gk;
            lds[j * (NH + 1) + lane] = Hn * gq;                         // y contribution
        }

        __syncthreads();   // RAW: all 64 steps' writes visible before row sums

        // phase C: lane t sums its timestep's row (conflict-free: consecutive floats, rows offset 65)
        if (lane < cnt) {
            const float* row = &lds[lane * (NH + 1)];
            float y0 = 0.f, y1 = 0.f, y2 = 0.f, y3 = 0.f;
            #pragma unroll
            for (int g = 0; g < NH; g += 4) {
                y0 += row[g + 0]; y1 += row[g + 1];
                y2 += row[g + 2]; y3 += row[g + 3];
            }
            out[(size_t)(t0 + lane) * ns + s] = (y0 + y1) + (y2 + y3);
        }
    }
}

extern "C" void kernel_launch(void* const* d_in, const int* in_sizes, int n_in,
                              void* d_out, int out_size, void* d_ws, size_t ws_size,
                              hipStream_t stream) {
    const float* x  = (const float*)d_in[0];
    const float* xc = (const float*)d_in[1];
    const float* W3 = (const float*)d_in[2];
    const float* b3 = (const float*)d_in[3];
    float* out = (float*)d_out;

    const int nh = in_sizes[3] / 4;            // 64
    const int ng = in_sizes[2] / (4 * nh);     // 32
    const int ns = in_sizes[1] / ng;           // 1024
    const int nt = in_sizes[0] / (ns * 4);     // 1000

    waternet_kernel<<<dim3(ns), dim3(64), 0, stream>>>(x, xc, W3, b3, out, nt, ns);
}

// Round 3
// 111.491 us; speedup vs baseline: 1.2772x; 1.2772x over previous
//
#include <hip/hip_runtime.h>
#include <math.h>

#define NH 64
#define NG 32
#define LROW (NH + 1)   // LDS row stride (pad +1: phase-C stride-65 reads are 2-way -> free)

// wave-uniform lane broadcast -> v_readlane (SGPR result, off the VGPR dep chain)
__device__ __forceinline__ float bcast(float v, int l) {
    return __int_as_float(__builtin_amdgcn_readlane(__float_as_int(v), l));
}

// One wave (64 lanes) per catchment s; lane = hidden index h. 1000-step recurrence,
// chunked 64 t at a time:
//  phase A: lane i computes forcing-derived (Ps,Pl,E,relu(Ta)) for step t0+i in parallel
//  phase B: 64 serial steps (FULLY UNROLLED, constant-lane readlanes), ds_write y-contrib
//  phase C: lane t row-sums its timestep's 64 contributions from padded LDS
// No __syncthreads: single-wave block, DS ops are program-ordered per wave; y-tile is
// double-buffered. Next chunk's x gather is prefetched under phase B.
__global__ __launch_bounds__(64) void waternet_kernel(
    const float* __restrict__ x,   // [nt, ns, 4] fp32: P,E,T1,T2
    const float* __restrict__ xc,  // [ns, NG]
    const float* __restrict__ W3,  // [4*NH, NG]
    const float* __restrict__ b3,  // [4*NH]
    float* __restrict__ out,       // [nt, ns]
    int nt, int ns)
{
    // XCD-contiguous catchment mapping: blocks with b%8==x land on XCD x (round-robin
    // dispatch heuristic); give each XCD a contiguous ns/8 range of s so each 64B line
    // of x/out is touched by exactly one XCD's L2 (kills 4x fetch / 8x write amplification).
    const int b    = blockIdx.x;
    const int s    = (b & 7) * (ns >> 3) + (b >> 3);
    const int lane = threadIdx.x;           // 0..63 == h

    __shared__ float ybuf[2][NH * LROW];

    // ---- static gates: w = xc[s,:] @ W3^T + b3 (coalesced float4 row loads) ----
    float wq[4];
    #pragma unroll
    for (int q = 0; q < 4; ++q) {
        const float4* row = reinterpret_cast<const float4*>(W3 + (size_t)(q * NH + lane) * NG);
        const float4* xr  = reinterpret_cast<const float4*>(xc + (size_t)s * NG);
        float a = 0.f;
        #pragma unroll
        for (int g = 0; g < NG / 4; ++g) {
            const float4 w  = row[g];
            const float4 xv = xr[g];
            a = fmaf(w.x, xv.x, a); a = fmaf(w.y, xv.y, a);
            a = fmaf(w.z, xv.z, a); a = fmaf(w.w, xv.w, a);
        }
        wq[q] = a + b3[q * NH + lane];
    }
    const float gm = expf(wq[0]) + 1.0f;               // melt gate (>1, positive)
    const float ge = 1.0f / (1.0f + expf(-wq[1]));     // ET gate
    const float go = 1.0f / (1.0f + expf(-wq[2]));     // outflow gate
    float mx = wq[3];
    #pragma unroll
    for (int o = 32; o; o >>= 1) mx = fmaxf(mx, __shfl_xor(mx, o, 64));
    const float ex = expf(wq[3] - mx);
    float smx = ex;
    #pragma unroll
    for (int o = 32; o; o >>= 1) smx += __shfl_xor(smx, o, 64);
    const float ga = ex / smx;                         // softmax over h
    const float gq = go * ga;                          // y contrib   = Hn * gq
    const float gk = 1.0f - go;                        // H carryover = Hn * gk

    float S = 0.f, H = 0.f;
    const int nchunk = (nt + NH - 1) / NH;

    // prefetch chunk 0's forcing (lane i -> timestep i)
    int tp = min(lane, nt - 1);
    float4 f = *reinterpret_cast<const float4*>(x + ((size_t)tp * ns + s) * 4);

    for (int c = 0; c < nchunk; ++c) {
        const int t0  = c * NH;
        const int cnt = min(NH, nt - t0);

        // ---- phase A: per-lane forcing for timestep t0+lane ----
        const float P = f.x, E = f.y, T1 = f.z, T2 = f.w;
        const float Ta  = 0.5f * (T1 + T2);
        const float arg = fminf(1.f, fmaxf(-1.f, (T1 + T2) / (T2 - T1)));   // T2>T1 guaranteed
        const float r   = 1.f - acosf(arg) * (1.0f / 3.1415f);              // module's PI
        const float rP  = (T1 >= 0.f) ? 1.f : ((T2 <= 0.f) ? 0.f : r);
        const float Ps  = (1.f - rP) * P;
        const float Pl  = rP * P;
        const float Tr  = fmaxf(Ta, 0.f);  // relu(Ta): relu(Ta*gm) == gm*relu(Ta) since gm>0

        // prefetch next chunk's gather (latency hidden under phase B)
        tp = min(t0 + NH + lane, nt - 1);
        const float4 fn = *reinterpret_cast<const float4*>(x + ((size_t)tp * ns + s) * 4);

        float* yb = ybuf[c & 1];

        #define STEP(J) { \
            const float Trj = bcast(Tr, (J)); \
            const float Psj = bcast(Ps, (J)); \
            const float Plj = bcast(Pl, (J)); \
            const float Ej  = bcast(E,  (J)); \
            const float Sm  = fminf(S, Trj * gm);            /* snowmelt */ \
            const float A   = fmaf(-Ej, ge, Plj);            /* net liquid in */ \
            const float Hn  = fmaxf(H + A + Sm, 0.f);        /* bucket */ \
            S = (S + Psj) - Sm; \
            H = Hn * gk; \
            yb[(J) * LROW + lane] = Hn * gq; \
        }

        // ---- phase B: serial recurrence, 64-wide over h ----
        if (cnt == NH) {
            #pragma unroll
            for (int j = 0; j < NH; ++j) STEP(j)
        } else {
            for (int j = 0; j < cnt; ++j) STEP(j)   // tail chunk (nt%64)
        }
        #undef STEP

        // ---- phase C: lane t sums its timestep's row (stride-65: 2-way, free) ----
        if (lane < cnt) {
            const float* row = &yb[lane * LROW];
            float y0 = 0.f, y1 = 0.f, y2 = 0.f, y3 = 0.f;
            #pragma unroll
            for (int g = 0; g < NH; g += 4) {
                y0 += row[g + 0]; y1 += row[g + 1];
                y2 += row[g + 2]; y3 += row[g + 3];
            }
            out[(size_t)(t0 + lane) * ns + s] = (y0 + y1) + (y2 + y3);
        }

        f = fn;
    }
}

extern "C" void kernel_launch(void* const* d_in, const int* in_sizes, int n_in,
                              void* d_out, int out_size, void* d_ws, size_t ws_size,
                              hipStream_t stream) {
    const float* x  = (const float*)d_in[0];
    const float* xc = (const float*)d_in[1];
    const float* W3 = (const float*)d_in[2];
    const float* b3 = (const float*)d_in[3];
    float* out = (float*)d_out;

    const int nh = in_sizes[3] / 4;            // 64
    const int ng = in_sizes[2] / (4 * nh);     // 32
    const int ns = in_sizes[1] / ng;           // 1024
    const int nt = in_sizes[0] / (ns * 4);     // 1000

    waternet_kernel<<<dim3(ns), dim3(64), 0, stream>>>(x, xc, W3, b3, out, nt, ns);
}